// Round 3
// baseline (314.769 us; speedup 1.0000x reference)
//
#include <hip/hip_runtime.h>
#include <stdint.h>

typedef unsigned short u16;
typedef __bf16 bf16x8 __attribute__((ext_vector_type(8)));
typedef float f32x4 __attribute__((ext_vector_type(4)));

typedef __attribute__((address_space(3))) void lds_void;
typedef const __attribute__((address_space(1))) void gbl_void;
#define GLD_LDS16(g, l) __builtin_amdgcn_global_load_lds((gbl_void*)(g), (lds_void*)(l), 16, 0, 0)

__device__ __forceinline__ u16 f2bf(float f) {
  unsigned u = __float_as_uint(f);
  u += 0x7fffu + ((u >> 16) & 1u);   // RNE
  return (u16)(u >> 16);
}

// pack bf16(a) | bf16(b)<<16 with round-half-up via v_perm_b32
__device__ __forceinline__ unsigned pk2bf(float a, float b) {
  unsigned au = __float_as_uint(a) + 0x8000u;
  unsigned bu = __float_as_uint(b) + 0x8000u;
  return __builtin_amdgcn_perm(bu, au, 0x07060302u);
}

// ---- fused prepass: all fp32 -> bf16 conversions in one launch ----
__global__ void k_convert_all(const float* __restrict__ inq, const float* __restrict__ r_q,
                              const float* __restrict__ inkv, const float* __restrict__ r_kv,
                              const float* __restrict__ w_q, const float* __restrict__ w_kv,
                              const float* __restrict__ w_o,
                              u16* __restrict__ Xq, u16* __restrict__ Xkv,
                              u16* __restrict__ Wq, u16* __restrict__ Wkv,
                              u16* __restrict__ Wo) {
  int blk = blockIdx.x;
  const float* src; const float* r = nullptr; u16* dst; int base;
  if (blk < 8192)       { src = inq;  r = r_q;  dst = Xq;  base = 0; }
  else if (blk < 16384) { src = inkv; r = r_kv; dst = Xkv; base = 8192; }
  else if (blk < 17408) { src = w_q;  dst = Wq;  base = 16384; }
  else if (blk < 19456) { src = w_kv; dst = Wkv; base = 17408; }
  else                  { src = w_o;  dst = Wo;  base = 19456; }
  int i4 = ((blk - base) * 256 + threadIdx.x) * 4;
  float4 xv = *(const float4*)(src + i4);
  if (r) {
    int rb = ((i4 >> 10) & 7) * 1024 + (i4 & 1023);
    float4 rv = *(const float4*)(r + rb);
    xv.x *= rv.x; xv.y *= rv.y; xv.z *= rv.z; xv.w *= rv.w;
  }
  unsigned long long pk = (unsigned long long)pk2bf(xv.x, xv.y)
      | ((unsigned long long)pk2bf(xv.z, xv.w) << 32);
  *(unsigned long long*)(dst + i4) = pk;
}

// ---- C = A * B^T, A: MxK bf16 row-major, B: NxK bf16 row-major ----
template <int MODE>
__global__ void k_gemm_bt(const u16* __restrict__ A, const u16* __restrict__ B,
                          void* __restrict__ Cout, const float* __restrict__ s,
                          const float* __restrict__ bias, int M, int N, int K,
                          float postscale) {
  __shared__ __align__(16) u16 As[128 * 32];
  __shared__ __align__(16) u16 Bs[128 * 32];
  const int tid = threadIdx.x;
  const int w = tid >> 6, lane = tid & 63;
  const int quad = lane >> 4, l16 = lane & 15;
  const int n0 = blockIdx.x * 128, m0 = blockIdx.y * 128;
  const int wm = (w & 1) * 64, wn = (w >> 1) * 64;

  f32x4 acc[4][4] = {};

  int srow[2], scol[2];
#pragma unroll
  for (int i = 0; i < 2; ++i) {
    int p = (w * 2 + i) * 64 + lane;
    int row = p >> 2;
    int cb = (p & 3) ^ ((row >> 1) & 3);
    srow[i] = row; scol[i] = cb * 8;
  }
  int offA[4], offB[4];
#pragma unroll
  for (int t = 0; t < 4; ++t) {
    int ra = wm + t * 16 + l16;
    offA[t] = ra * 32 + ((quad ^ ((ra >> 1) & 3)) * 8);
    int rb = wn + t * 16 + l16;
    offB[t] = rb * 32 + ((quad ^ ((rb >> 1) & 3)) * 8);
  }

  for (int k0 = 0; k0 < K; k0 += 32) {
#pragma unroll
    for (int i = 0; i < 2; ++i) {
      GLD_LDS16(A + (size_t)(m0 + srow[i]) * K + k0 + scol[i], As + (w * 2 + i) * 512);
      GLD_LDS16(B + (size_t)(n0 + srow[i]) * K + k0 + scol[i], Bs + (w * 2 + i) * 512);
    }
    __syncthreads();
    bf16x8 af[4], bfr[4];
#pragma unroll
    for (int mt = 0; mt < 4; ++mt) af[mt] = *(const bf16x8*)(As + offA[mt]);
#pragma unroll
    for (int nt = 0; nt < 4; ++nt) bfr[nt] = *(const bf16x8*)(Bs + offB[nt]);
#pragma unroll
    for (int mt = 0; mt < 4; ++mt)
#pragma unroll
      for (int nt = 0; nt < 4; ++nt)
        acc[mt][nt] = __builtin_amdgcn_mfma_f32_16x16x32_bf16(af[mt], bfr[nt], acc[mt][nt], 0, 0, 0);
    __syncthreads();
  }

#pragma unroll
  for (int mt = 0; mt < 4; ++mt)
#pragma unroll
    for (int nt = 0; nt < 4; ++nt) {
      int n = n0 + wn + nt * 16 + l16;
#pragma unroll
      for (int rg = 0; rg < 4; ++rg) {
        int m = m0 + wm + mt * 16 + quad * 4 + rg;
        float v = acc[mt][nt][rg];
        if (MODE == 0) {
          v = (v * s[(m & 7) * N + n] + bias[n]) * postscale;
          ((u16*)Cout)[(size_t)m * N + n] = f2bf(v);
        } else {
          ((float*)Cout)[(size_t)m * N + n] = v + bias[n];
        }
      }
    }
}

// ---- V transpose: kv(t,n,c=1,d) -> Vt[n][d][t] ----
__global__ void k_transpose_v(const u16* __restrict__ kv, u16* __restrict__ vt) {
  __shared__ __align__(16) u16 tile[64][72];
  const int tid = threadIdx.x;
  const int n = blockIdx.x >> 4;
  const int t0 = (blockIdx.x & 15) << 6;
#pragma unroll
  for (int it = 0; it < 2; ++it) {
    int r = it * 32 + (tid >> 3);
    int c = (tid & 7) << 3;
    *(uint4*)&tile[r][c] = *(const uint4*)(kv + ((size_t)(t0 + r) * 128 + n) * 128 + 64 + c);
  }
  __syncthreads();
#pragma unroll
  for (int it = 0; it < 2; ++it) {
    int d = it * 32 + (tid >> 3);
    int tc = (tid & 7) << 3;
    u16 v[8];
#pragma unroll
    for (int j = 0; j < 8; ++j) v[j] = tile[tc + j][d];
    uint4 o;
    o.x = (unsigned)v[0] | ((unsigned)v[1] << 16);
    o.y = (unsigned)v[2] | ((unsigned)v[3] << 16);
    o.z = (unsigned)v[4] | ((unsigned)v[5] << 16);
    o.w = (unsigned)v[6] | ((unsigned)v[7] << 16);
    *(uint4*)(vt + ((size_t)n * 64 + d) * 1024 + t0 + tc) = o;
  }
}

// ---- flash attention, double-buffered K/V staging, 1 barrier per k-tile ----
// block = (q-chunk major, head minor): head n's 8 q-blocks land on XCD n%8
// so each head's K/V is fetched once per XCD (L2 locality).
__global__ __launch_bounds__(512, 4) void k_attn(const u16* __restrict__ qb,
                                                 const u16* __restrict__ kvb,
                                                 const u16* __restrict__ vtb,
                                                 u16* __restrict__ ctx) {
  __shared__ __align__(16) u16 Ks[2][64 * 64];
  __shared__ __align__(16) u16 Vts[2][64 * 64];
  __shared__ __align__(16) u16 Ps[8][16 * 72];   // per wave [qcol][kj], stride 72

  const int tid = threadIdx.x;
  const int w = tid >> 6, lane = tid & 63;
  const int quad = lane >> 4, l16 = lane & 15;
  const int n = blockIdx.x & 127;          // head (XCD-swizzled)
  const int q0 = (blockIdx.x >> 7) << 7;   // q-chunk
  const int tq = q0 + w * 16 + l16;

  bf16x8 bq[2];
#pragma unroll
  for (int ks = 0; ks < 2; ++ks)
    bq[ks] = *(const bf16x8*)(qb + ((size_t)tq * 128 + n) * 64 + ks * 32 + quad * 8);

  const int wv = w & 3;
  int sr[2], scb[2];
#pragma unroll
  for (int i = 0; i < 2; ++i) {
    int p = (wv * 2 + i) * 64 + lane;
    sr[i] = p >> 3;
    scb[i] = ((p & 7) ^ (sr[i] & 7)) * 8;
  }

  // stage k-tile tk0 into buffer `buf`
  const bool isK = (w < 4);
  const u16* gbase[2];
  u16* lbase[2];
#pragma unroll
  for (int i = 0; i < 2; ++i) {
    if (isK) {
      gbase[i] = kvb + ((size_t)sr[i] * 128 + n) * 128 + scb[i];   // + tk0*16384
      lbase[i] = &Ks[0][(wv * 2 + i) * 512];
    } else {
      gbase[i] = vtb + ((size_t)n * 64 + sr[i]) * 1024 + scb[i];   // + tk0
      lbase[i] = &Vts[0][(wv * 2 + i) * 512];
    }
  }
  const size_t gstep = isK ? 16384 : 1;   // per-key-element advance of global ptr
  const int lstep = 64 * 64;              // u16 per LDS buffer

  float l_i = 0.f;
  f32x4 accO[4] = {};
  u16* myP = Ps[w];
  const int pbase = l16 * 72;

  // prefetch tile 0
#pragma unroll
  for (int i = 0; i < 2; ++i) GLD_LDS16(gbase[i], lbase[i]);

#pragma unroll 1
  for (int tk0 = 0; tk0 < 1024; tk0 += 64) {
    const int cur = (tk0 >> 6) & 1;
    __syncthreads();   // drains this tile's loads (they had a full iter in flight)

    if (tk0 < 960) {   // issue next tile's loads into the other buffer
      size_t goff = (size_t)(tk0 + 64) * gstep;
#pragma unroll
      for (int i = 0; i < 2; ++i)
        GLD_LDS16(gbase[i] + goff, lbase[i] + (cur ^ 1) * lstep);
    }

    const u16* Kc = Ks[cur];
    const u16* Vc = Vts[cur];

    f32x4 accS[4] = {};
#pragma unroll
    for (int mt = 0; mt < 4; ++mt) {
      int r = mt * 16 + l16;
#pragma unroll
      for (int ks = 0; ks < 2; ++ks) {
        bf16x8 ak = *(const bf16x8*)(Kc + r * 64 + (((ks * 4 + quad) ^ (r & 7)) << 3));
        accS[mt] = __builtin_amdgcn_mfma_f32_16x16x32_bf16(ak, bq[ks], accS[mt], 0, 0, 0);
      }
    }

    // P = 2^s2 (q pre-scaled by 0.125*log2e); fixed-base softmax
    float pv[16];
    float s0 = 0.f, s1 = 0.f;
#pragma unroll
    for (int mt = 0; mt < 4; ++mt)
#pragma unroll
      for (int rg = 0; rg < 4; ++rg) {
        float p = __builtin_amdgcn_exp2f(accS[mt][rg]);
        pv[mt * 4 + rg] = p;
        if (rg & 1) s1 += p; else s0 += p;
      }
    float ssum = s0 + s1;
    ssum += __shfl_xor(ssum, 16);
    ssum += __shfl_xor(ssum, 32);
    l_i += ssum;

#pragma unroll
    for (int mt = 0; mt < 4; ++mt) {
      unsigned long long pk = (unsigned long long)pk2bf(pv[mt * 4 + 0], pv[mt * 4 + 1])
          | ((unsigned long long)pk2bf(pv[mt * 4 + 2], pv[mt * 4 + 3]) << 32);
      *(unsigned long long*)(myP + pbase + mt * 16 + quad * 4) = pk;
    }
#pragma unroll
    for (int dt = 0; dt < 4; ++dt) {
      int r = dt * 16 + l16;
#pragma unroll
      for (int ks = 0; ks < 2; ++ks) {
        bf16x8 av = *(const bf16x8*)(Vc + r * 64 + (((ks * 4 + quad) ^ (r & 7)) << 3));
        bf16x8 bp = *(const bf16x8*)(myP + pbase + ks * 32 + quad * 8);
        accO[dt] = __builtin_amdgcn_mfma_f32_16x16x32_bf16(av, bp, accO[dt], 0, 0, 0);
      }
    }
  }

  float inv = 1.f / l_i;
#pragma unroll
  for (int dt = 0; dt < 4; ++dt) {
    unsigned long long pk = (unsigned long long)pk2bf(accO[dt][0] * inv, accO[dt][1] * inv)
        | ((unsigned long long)pk2bf(accO[dt][2] * inv, accO[dt][3] * inv) << 32);
    *(unsigned long long*)(ctx + ((size_t)tq * 128 + n) * 64 + dt * 16 + quad * 4) = pk;
  }
}

extern "C" void kernel_launch(void* const* d_in, const int* in_sizes, int n_in,
                              void* d_out, int out_size, void* d_ws, size_t ws_size,
                              hipStream_t stream) {
  const float* inq  = (const float*)d_in[0];
  const float* inkv = (const float*)d_in[1];
  const float* w_q  = (const float*)d_in[2];
  const float* b_q  = (const float*)d_in[3];
  const float* w_kv = (const float*)d_in[4];
  const float* b_kv = (const float*)d_in[5];
  const float* w_o  = (const float*)d_in[6];
  const float* b_o  = (const float*)d_in[7];
  const float* r_q  = (const float*)d_in[8];
  const float* s_q  = (const float*)d_in[9];
  const float* r_kv = (const float*)d_in[10];
  const float* s_kv = (const float*)d_in[11];

  const size_t MEG = 1024 * 1024;
  u16* ws    = (u16*)d_ws;
  u16* Xq    = ws;               // 8M bf16, later reused as ctx
  u16* Xkv   = ws + 8 * MEG;     // 8M bf16, later reused as Vt
  u16* Wq    = ws + 16 * MEG;    // 1M
  u16* Wkv   = ws + 17 * MEG;    // 2M
  u16* Wo    = ws + 19 * MEG;    // 1M
  u16* qbuf  = ws + 20 * MEG;    // 8M  (t,n,d)
  u16* kvbuf = ws + 28 * MEG;    // 16M (t,n,c,d)
  u16* vt    = Xkv;
  u16* ctx   = Xq;

  k_convert_all<<<20480, 256, 0, stream>>>(inq, r_q, inkv, r_kv, w_q, w_kv, w_o,
                                           Xq, Xkv, Wq, Wkv, Wo);

  const float QSCALE = 0.125f * 1.44269504088896340736f;  // hd^-0.5 * log2e into q
  k_gemm_bt<0><<<dim3(8, 64), 256, 0, stream>>>(Xq, Wq, qbuf, s_q, b_q, 8192, 1024, 1024, QSCALE);
  k_gemm_bt<0><<<dim3(16, 64), 256, 0, stream>>>(Xkv, Wkv, kvbuf, s_kv, b_kv, 8192, 2048, 1024, 1.0f);
  k_transpose_v<<<2048, 256, 0, stream>>>(kvbuf, vt);
  k_attn<<<1024, 512, 0, stream>>>(qbuf, kvbuf, vt, ctx);
  k_gemm_bt<1><<<dim3(8, 64), 256, 0, stream>>>(ctx, Wo, d_out, nullptr, b_o, 8192, 1024, 1024, 1.0f);
}

// Round 4
// 299.953 us; speedup vs baseline: 1.0494x; 1.0494x over previous
//
#include <hip/hip_runtime.h>
#include <stdint.h>

typedef unsigned short u16;
typedef __bf16 bf16x8 __attribute__((ext_vector_type(8)));
typedef float f32x4 __attribute__((ext_vector_type(4)));

typedef __attribute__((address_space(3))) void lds_void;
typedef const __attribute__((address_space(1))) void gbl_void;
#define GLD_LDS16(g, l) __builtin_amdgcn_global_load_lds((gbl_void*)(g), (lds_void*)(l), 16, 0, 0)

__device__ __forceinline__ u16 f2bf(float f) {
  unsigned u = __float_as_uint(f);
  u += 0x7fffu + ((u >> 16) & 1u);   // RNE
  return (u16)(u >> 16);
}

// pack bf16(a) | bf16(b)<<16 with round-half-up via v_perm_b32
__device__ __forceinline__ unsigned pk2bf(float a, float b) {
  unsigned au = __float_as_uint(a) + 0x8000u;
  unsigned bu = __float_as_uint(b) + 0x8000u;
  return __builtin_amdgcn_perm(bu, au, 0x07060302u);
}

// ---- fused prepass: all fp32 -> bf16 conversions in one launch ----
__global__ void k_convert_all(const float* __restrict__ inq, const float* __restrict__ r_q,
                              const float* __restrict__ inkv, const float* __restrict__ r_kv,
                              const float* __restrict__ w_q, const float* __restrict__ w_kv,
                              const float* __restrict__ w_o,
                              u16* __restrict__ Xq, u16* __restrict__ Xkv,
                              u16* __restrict__ Wq, u16* __restrict__ Wkv,
                              u16* __restrict__ Wo) {
  int blk = blockIdx.x;
  const float* src; const float* r = nullptr; u16* dst; int base;
  if (blk < 8192)       { src = inq;  r = r_q;  dst = Xq;  base = 0; }
  else if (blk < 16384) { src = inkv; r = r_kv; dst = Xkv; base = 8192; }
  else if (blk < 17408) { src = w_q;  dst = Wq;  base = 16384; }
  else if (blk < 19456) { src = w_kv; dst = Wkv; base = 17408; }
  else                  { src = w_o;  dst = Wo;  base = 19456; }
  int i4 = ((blk - base) * 256 + threadIdx.x) * 4;
  float4 xv = *(const float4*)(src + i4);
  if (r) {
    int rb = ((i4 >> 10) & 7) * 1024 + (i4 & 1023);
    float4 rv = *(const float4*)(r + rb);
    xv.x *= rv.x; xv.y *= rv.y; xv.z *= rv.z; xv.w *= rv.w;
  }
  unsigned long long pk = (unsigned long long)pk2bf(xv.x, xv.y)
      | ((unsigned long long)pk2bf(xv.z, xv.w) << 32);
  *(unsigned long long*)(dst + i4) = pk;
}

// ---- GEMM tile body: C = A * B^T, double-buffered LDS, 128x128 tile, BK=32 ----
// MODE 0: bf16 out, C = (acc * s[(m&7)*N+n] + bias[n]) * postscale
// MODE 1: f32 out,  C = acc + bias[n]
template <int MODE>
__device__ __forceinline__ void gemm_tile(const u16* __restrict__ A, const u16* __restrict__ B,
                                          void* __restrict__ Cout, const float* __restrict__ s,
                                          const float* __restrict__ bias, int N, int K,
                                          float postscale, int bx, int by,
                                          u16* As, u16* Bs, int tid) {
  const int w = tid >> 6, lane = tid & 63;
  const int quad = lane >> 4, l16 = lane & 15;
  const int n0 = bx * 128, m0 = by * 128;
  const int wm = (w & 1) * 64, wn = (w >> 1) * 64;

  f32x4 acc[4][4] = {};

  int srow[2], scol[2];
#pragma unroll
  for (int i = 0; i < 2; ++i) {
    int p = (w * 2 + i) * 64 + lane;
    int row = p >> 2;
    int cb = (p & 3) ^ ((row >> 1) & 3);
    srow[i] = row; scol[i] = cb * 8;
  }
  int offA[4], offB[4];
#pragma unroll
  for (int t = 0; t < 4; ++t) {
    int ra = wm + t * 16 + l16;
    offA[t] = ra * 32 + ((quad ^ ((ra >> 1) & 3)) * 8);
    int rb = wn + t * 16 + l16;
    offB[t] = rb * 32 + ((quad ^ ((rb >> 1) & 3)) * 8);
  }

  // prefetch k-tile 0 into buffer 0
#pragma unroll
  for (int i = 0; i < 2; ++i) {
    GLD_LDS16(A + (size_t)(m0 + srow[i]) * K + scol[i], As + (w * 2 + i) * 512);
    GLD_LDS16(B + (size_t)(n0 + srow[i]) * K + scol[i], Bs + (w * 2 + i) * 512);
  }

  for (int k0 = 0; k0 < K; k0 += 32) {
    const int cur = (k0 >> 5) & 1;
    __syncthreads();
    if (k0 + 32 < K) {
#pragma unroll
      for (int i = 0; i < 2; ++i) {
        GLD_LDS16(A + (size_t)(m0 + srow[i]) * K + (k0 + 32) + scol[i],
                  As + (cur ^ 1) * 4096 + (w * 2 + i) * 512);
        GLD_LDS16(B + (size_t)(n0 + srow[i]) * K + (k0 + 32) + scol[i],
                  Bs + (cur ^ 1) * 4096 + (w * 2 + i) * 512);
      }
    }
    const u16* Ac = As + cur * 4096;
    const u16* Bc = Bs + cur * 4096;
    bf16x8 af[4], bfr[4];
#pragma unroll
    for (int mt = 0; mt < 4; ++mt) af[mt] = *(const bf16x8*)(Ac + offA[mt]);
#pragma unroll
    for (int nt = 0; nt < 4; ++nt) bfr[nt] = *(const bf16x8*)(Bc + offB[nt]);
#pragma unroll
    for (int mt = 0; mt < 4; ++mt)
#pragma unroll
      for (int nt = 0; nt < 4; ++nt)
        acc[mt][nt] = __builtin_amdgcn_mfma_f32_16x16x32_bf16(af[mt], bfr[nt], acc[mt][nt], 0, 0, 0);
  }

#pragma unroll
  for (int mt = 0; mt < 4; ++mt)
#pragma unroll
    for (int nt = 0; nt < 4; ++nt) {
      int n = n0 + wn + nt * 16 + l16;
#pragma unroll
      for (int rg = 0; rg < 4; ++rg) {
        int m = m0 + wm + mt * 16 + quad * 4 + rg;
        float v = acc[mt][nt][rg];
        if (MODE == 0) {
          v = (v * s[(m & 7) * N + n] + bias[n]) * postscale;
          ((u16*)Cout)[(size_t)m * N + n] = f2bf(v);
        } else {
          ((float*)Cout)[(size_t)m * N + n] = v + bias[n];
        }
      }
    }
}

// fused q + kv projection GEMMs: blockIdx.x < 8 -> q (N=1024), else kv (N=2048)
__global__ void k_gemm_qkv(const u16* __restrict__ Xq, const u16* __restrict__ Wq,
                           u16* __restrict__ qout, const float* __restrict__ s_q,
                           const float* __restrict__ b_q, float qscale,
                           const u16* __restrict__ Xkv, const u16* __restrict__ Wkv,
                           u16* __restrict__ kvout, const float* __restrict__ s_kv,
                           const float* __restrict__ b_kv) {
  __shared__ __align__(16) u16 As[2 * 4096];
  __shared__ __align__(16) u16 Bs[2 * 4096];
  if (blockIdx.x < 8)
    gemm_tile<0>(Xq, Wq, qout, s_q, b_q, 1024, 1024, qscale, blockIdx.x, blockIdx.y, As, Bs, threadIdx.x);
  else
    gemm_tile<0>(Xkv, Wkv, kvout, s_kv, b_kv, 2048, 1024, 1.0f, blockIdx.x - 8, blockIdx.y, As, Bs, threadIdx.x);
}

// output projection GEMM (fp32 out)
__global__ void k_gemm_o(const u16* __restrict__ A, const u16* __restrict__ B,
                         float* __restrict__ Cout, const float* __restrict__ bias) {
  __shared__ __align__(16) u16 As[2 * 4096];
  __shared__ __align__(16) u16 Bs[2 * 4096];
  gemm_tile<1>(A, B, Cout, nullptr, bias, 1024, 1024, 1.0f, blockIdx.x, blockIdx.y, As, Bs, threadIdx.x);
}

// ---- V transpose: kv(t,n,c=1,d) -> Vt[n][d][t] ----
__global__ void k_transpose_v(const u16* __restrict__ kv, u16* __restrict__ vt) {
  __shared__ __align__(16) u16 tile[64][72];
  const int tid = threadIdx.x;
  const int n = blockIdx.x >> 4;
  const int t0 = (blockIdx.x & 15) << 6;
#pragma unroll
  for (int it = 0; it < 2; ++it) {
    int r = it * 32 + (tid >> 3);
    int c = (tid & 7) << 3;
    *(uint4*)&tile[r][c] = *(const uint4*)(kv + ((size_t)(t0 + r) * 128 + n) * 128 + 64 + c);
  }
  __syncthreads();
#pragma unroll
  for (int it = 0; it < 2; ++it) {
    int d = it * 32 + (tid >> 3);
    int tc = (tid & 7) << 3;
    u16 v[8];
#pragma unroll
    for (int j = 0; j < 8; ++j) v[j] = tile[tc + j][d];
    uint4 o;
    o.x = (unsigned)v[0] | ((unsigned)v[1] << 16);
    o.y = (unsigned)v[2] | ((unsigned)v[3] << 16);
    o.z = (unsigned)v[4] | ((unsigned)v[5] << 16);
    o.w = (unsigned)v[6] | ((unsigned)v[7] << 16);
    *(uint4*)(vt + ((size_t)n * 64 + d) * 1024 + t0 + tc) = o;
  }
}

// ---- flash attention, G=2: 4 waves x 32 q-cols per 128-q block ----
// Each K/V fragment read from LDS feeds 2 MFMAs -> half the K/V LDS traffic.
// Double-buffered K/V staging (1 barrier/k-tile), XCD swizzle on head index.
__global__ __launch_bounds__(256, 3) void k_attn(const u16* __restrict__ qb,
                                                 const u16* __restrict__ kvb,
                                                 const u16* __restrict__ vtb,
                                                 u16* __restrict__ ctx) {
  __shared__ __align__(16) u16 Ks[2][4096];
  __shared__ __align__(16) u16 Vts[2][4096];
  __shared__ __align__(16) u16 Ps[4][32 * 72];  // per wave [q 0..31][key 0..63], stride 72

  const int tid = threadIdx.x;
  const int w = tid >> 6, lane = tid & 63;
  const int quad = lane >> 4, l16 = lane & 15;
  const int n = blockIdx.x & 127;          // head (XCD-swizzled)
  const int q0 = (blockIdx.x >> 7) << 7;   // q-chunk
  const int qw = q0 + w * 32;

  bf16x8 bq[2][2];
#pragma unroll
  for (int g = 0; g < 2; ++g)
#pragma unroll
    for (int ks = 0; ks < 2; ++ks)
      bq[g][ks] = *(const bf16x8*)(qb + ((size_t)(qw + g * 16 + l16) * 128 + n) * 64 + ks * 32 + quad * 8);

  // staging: waves 0-1 -> K tile (8 KB), waves 2-3 -> V tile; 4 chunks each lane
  const bool isK = (w < 2);
  const int wv = w & 1;
  const u16* gbase[4];
  u16* lbase[4];
#pragma unroll
  for (int i = 0; i < 4; ++i) {
    int p = (wv * 4 + i) * 64 + lane;     // 16B chunk in 8KB tile (512 total)
    int r = p >> 3;
    int scb = ((p & 7) ^ (r & 7)) * 8;
    if (isK) {
      gbase[i] = kvb + ((size_t)r * 128 + n) * 128 + scb;   // + tk*16384
      lbase[i] = &Ks[0][(wv * 4 + i) * 512];
    } else {
      gbase[i] = vtb + ((size_t)n * 64 + r) * 1024 + scb;   // + tk
      lbase[i] = &Vts[0][(wv * 4 + i) * 512];
    }
  }
  const size_t gstep = isK ? 16384 : 1;
  const int lstep = 4096;

  float l_i[2] = {0.f, 0.f};
  f32x4 accO[2][4] = {};
  u16* myP = Ps[w];

  // prefetch tile 0
#pragma unroll
  for (int i = 0; i < 4; ++i) GLD_LDS16(gbase[i], lbase[i]);

#pragma unroll 1
  for (int tk0 = 0; tk0 < 1024; tk0 += 64) {
    const int cur = (tk0 >> 6) & 1;
    __syncthreads();
    if (tk0 < 960) {
      size_t goff = (size_t)(tk0 + 64) * gstep;
#pragma unroll
      for (int i = 0; i < 4; ++i)
        GLD_LDS16(gbase[i] + goff, lbase[i] + (cur ^ 1) * lstep);
    }
    const u16* Kc = Ks[cur];
    const u16* Vc = Vts[cur];

    // S^T = K . Q^T for both q-groups, sharing each K fragment
    f32x4 accS[2][4] = {};
#pragma unroll
    for (int mt = 0; mt < 4; ++mt) {
      int r = mt * 16 + l16;
#pragma unroll
      for (int ks = 0; ks < 2; ++ks) {
        bf16x8 ak = *(const bf16x8*)(Kc + r * 64 + (((ks * 4 + quad) ^ (r & 7)) << 3));
#pragma unroll
        for (int g = 0; g < 2; ++g)
          accS[g][mt] = __builtin_amdgcn_mfma_f32_16x16x32_bf16(ak, bq[g][ks], accS[g][mt], 0, 0, 0);
      }
    }

    // fixed-base softmax (q pre-scaled by 0.125*log2e) + P store, per group
#pragma unroll
    for (int g = 0; g < 2; ++g) {
      float pv[16];
      float ss = 0.f;
#pragma unroll
      for (int mt = 0; mt < 4; ++mt)
#pragma unroll
        for (int rg = 0; rg < 4; ++rg) {
          float p = __builtin_amdgcn_exp2f(accS[g][mt][rg]);
          pv[mt * 4 + rg] = p;
          ss += p;
        }
      ss += __shfl_xor(ss, 16);
      ss += __shfl_xor(ss, 32);
      l_i[g] += ss;
      const int prow = (g * 16 + l16) * 72;
#pragma unroll
      for (int mt = 0; mt < 4; ++mt) {
        unsigned long long pk = (unsigned long long)pk2bf(pv[mt * 4 + 0], pv[mt * 4 + 1])
            | ((unsigned long long)pk2bf(pv[mt * 4 + 2], pv[mt * 4 + 3]) << 32);
        *(unsigned long long*)(myP + prow + mt * 16 + quad * 4) = pk;
      }
    }

    // O^T += V^T . P^T, sharing each V fragment across groups
    bf16x8 bp[2][2];
#pragma unroll
    for (int g = 0; g < 2; ++g)
#pragma unroll
      for (int ks = 0; ks < 2; ++ks)
        bp[g][ks] = *(const bf16x8*)(myP + (g * 16 + l16) * 72 + ks * 32 + quad * 8);
#pragma unroll
    for (int dt = 0; dt < 4; ++dt) {
      int r = dt * 16 + l16;
#pragma unroll
      for (int ks = 0; ks < 2; ++ks) {
        bf16x8 av = *(const bf16x8*)(Vc + r * 64 + (((ks * 4 + quad) ^ (r & 7)) << 3));
#pragma unroll
        for (int g = 0; g < 2; ++g)
          accO[g][dt] = __builtin_amdgcn_mfma_f32_16x16x32_bf16(av, bp[g][ks], accO[g][dt], 0, 0, 0);
      }
    }
  }

#pragma unroll
  for (int g = 0; g < 2; ++g) {
    float inv = 1.f / l_i[g];
    const size_t obase = ((size_t)(qw + g * 16 + l16) * 128 + n) * 64;
#pragma unroll
    for (int dt = 0; dt < 4; ++dt) {
      unsigned long long pk = (unsigned long long)pk2bf(accO[g][dt][0] * inv, accO[g][dt][1] * inv)
          | ((unsigned long long)pk2bf(accO[g][dt][2] * inv, accO[g][dt][3] * inv) << 32);
      *(unsigned long long*)(ctx + obase + dt * 16 + quad * 4) = pk;
    }
  }
}

extern "C" void kernel_launch(void* const* d_in, const int* in_sizes, int n_in,
                              void* d_out, int out_size, void* d_ws, size_t ws_size,
                              hipStream_t stream) {
  const float* inq  = (const float*)d_in[0];
  const float* inkv = (const float*)d_in[1];
  const float* w_q  = (const float*)d_in[2];
  const float* b_q  = (const float*)d_in[3];
  const float* w_kv = (const float*)d_in[4];
  const float* b_kv = (const float*)d_in[5];
  const float* w_o  = (const float*)d_in[6];
  const float* b_o  = (const float*)d_in[7];
  const float* r_q  = (const float*)d_in[8];
  const float* s_q  = (const float*)d_in[9];
  const float* r_kv = (const float*)d_in[10];
  const float* s_kv = (const float*)d_in[11];

  const size_t MEG = 1024 * 1024;
  u16* ws    = (u16*)d_ws;
  u16* Xq    = ws;               // 8M bf16, later reused as ctx
  u16* Xkv   = ws + 8 * MEG;     // 8M bf16, later reused as Vt
  u16* Wq    = ws + 16 * MEG;    // 1M
  u16* Wkv   = ws + 17 * MEG;    // 2M
  u16* Wo    = ws + 19 * MEG;    // 1M
  u16* qbuf  = ws + 20 * MEG;    // 8M  (t,n,d)
  u16* kvbuf = ws + 28 * MEG;    // 16M (t,n,c,d)
  u16* vt    = Xkv;
  u16* ctx   = Xq;

  k_convert_all<<<20480, 256, 0, stream>>>(inq, r_q, inkv, r_kv, w_q, w_kv, w_o,
                                           Xq, Xkv, Wq, Wkv, Wo);

  const float QSCALE = 0.125f * 1.44269504088896340736f;  // hd^-0.5 * log2e into q
  k_gemm_qkv<<<dim3(24, 64), 256, 0, stream>>>(Xq, Wq, qbuf, s_q, b_q, QSCALE,
                                               Xkv, Wkv, kvbuf, s_kv, b_kv);
  k_transpose_v<<<2048, 256, 0, stream>>>(kvbuf, vt);
  k_attn<<<1024, 256, 0, stream>>>(qbuf, kvbuf, vt, ctx);
  k_gemm_o<<<dim3(8, 64), 256, 0, stream>>>(ctx, Wo, (float*)d_out, b_o);
}

// Round 5
// 296.935 us; speedup vs baseline: 1.0601x; 1.0102x over previous
//
#include <hip/hip_runtime.h>
#include <stdint.h>

typedef unsigned short u16;
typedef __bf16 bf16x8 __attribute__((ext_vector_type(8)));
typedef float f32x4 __attribute__((ext_vector_type(4)));

typedef __attribute__((address_space(3))) void lds_void;
typedef const __attribute__((address_space(1))) void gbl_void;
#define GLD_LDS16(g, l) __builtin_amdgcn_global_load_lds((gbl_void*)(g), (lds_void*)(l), 16, 0, 0)

__device__ __forceinline__ u16 f2bf(float f) {
  unsigned u = __float_as_uint(f);
  u += 0x7fffu + ((u >> 16) & 1u);   // RNE
  return (u16)(u >> 16);
}

// pack bf16(a) | bf16(b)<<16 with round-half-up via v_perm_b32
__device__ __forceinline__ unsigned pk2bf(float a, float b) {
  unsigned au = __float_as_uint(a) + 0x8000u;
  unsigned bu = __float_as_uint(b) + 0x8000u;
  return __builtin_amdgcn_perm(bu, au, 0x07060302u);
}

// ---- fused prepass: all fp32 -> bf16 conversions in one launch ----
__global__ void k_convert_all(const float* __restrict__ inq, const float* __restrict__ r_q,
                              const float* __restrict__ inkv, const float* __restrict__ r_kv,
                              const float* __restrict__ w_q, const float* __restrict__ w_kv,
                              const float* __restrict__ w_o,
                              u16* __restrict__ Xq, u16* __restrict__ Xkv,
                              u16* __restrict__ Wq, u16* __restrict__ Wkv,
                              u16* __restrict__ Wo) {
  int blk = blockIdx.x;
  const float* src; const float* r = nullptr; u16* dst; int base;
  if (blk < 8192)       { src = inq;  r = r_q;  dst = Xq;  base = 0; }
  else if (blk < 16384) { src = inkv; r = r_kv; dst = Xkv; base = 8192; }
  else if (blk < 17408) { src = w_q;  dst = Wq;  base = 16384; }
  else if (blk < 19456) { src = w_kv; dst = Wkv; base = 17408; }
  else                  { src = w_o;  dst = Wo;  base = 19456; }
  int i4 = ((blk - base) * 256 + threadIdx.x) * 4;
  float4 xv = *(const float4*)(src + i4);
  if (r) {
    int rb = ((i4 >> 10) & 7) * 1024 + (i4 & 1023);
    float4 rv = *(const float4*)(r + rb);
    xv.x *= rv.x; xv.y *= rv.y; xv.z *= rv.z; xv.w *= rv.w;
  }
  unsigned long long pk = (unsigned long long)pk2bf(xv.x, xv.y)
      | ((unsigned long long)pk2bf(xv.z, xv.w) << 32);
  *(unsigned long long*)(dst + i4) = pk;
}

// ---- GEMM tile body: C = A * B^T, double-buffered LDS, 128x128 tile, BK=32 ----
// MODE 0: bf16 out, C = (acc * s[(m&7)*N+n] + bias[n]) * postscale
// MODE 1: f32 out,  C = acc + bias[n]
template <int MODE>
__device__ __forceinline__ void gemm_tile(const u16* __restrict__ A, const u16* __restrict__ B,
                                          void* __restrict__ Cout, const float* __restrict__ s,
                                          const float* __restrict__ bias, int N, int K,
                                          float postscale, int bx, int by,
                                          u16* As, u16* Bs, int tid) {
  const int w = tid >> 6, lane = tid & 63;
  const int quad = lane >> 4, l16 = lane & 15;
  const int n0 = bx * 128, m0 = by * 128;
  const int wm = (w & 1) * 64, wn = (w >> 1) * 64;

  f32x4 acc[4][4] = {};

  int srow[2], scol[2];
#pragma unroll
  for (int i = 0; i < 2; ++i) {
    int p = (w * 2 + i) * 64 + lane;
    int row = p >> 2;
    int cb = (p & 3) ^ ((row >> 1) & 3);
    srow[i] = row; scol[i] = cb * 8;
  }
  int offA[4], offB[4];
#pragma unroll
  for (int t = 0; t < 4; ++t) {
    int ra = wm + t * 16 + l16;
    offA[t] = ra * 32 + ((quad ^ ((ra >> 1) & 3)) * 8);
    int rb = wn + t * 16 + l16;
    offB[t] = rb * 32 + ((quad ^ ((rb >> 1) & 3)) * 8);
  }

  // prefetch k-tile 0 into buffer 0
#pragma unroll
  for (int i = 0; i < 2; ++i) {
    GLD_LDS16(A + (size_t)(m0 + srow[i]) * K + scol[i], As + (w * 2 + i) * 512);
    GLD_LDS16(B + (size_t)(n0 + srow[i]) * K + scol[i], Bs + (w * 2 + i) * 512);
  }

  for (int k0 = 0; k0 < K; k0 += 32) {
    const int cur = (k0 >> 5) & 1;
    __syncthreads();
    if (k0 + 32 < K) {
#pragma unroll
      for (int i = 0; i < 2; ++i) {
        GLD_LDS16(A + (size_t)(m0 + srow[i]) * K + (k0 + 32) + scol[i],
                  As + (cur ^ 1) * 4096 + (w * 2 + i) * 512);
        GLD_LDS16(B + (size_t)(n0 + srow[i]) * K + (k0 + 32) + scol[i],
                  Bs + (cur ^ 1) * 4096 + (w * 2 + i) * 512);
      }
    }
    const u16* Ac = As + cur * 4096;
    const u16* Bc = Bs + cur * 4096;
    bf16x8 af[4], bfr[4];
#pragma unroll
    for (int mt = 0; mt < 4; ++mt) af[mt] = *(const bf16x8*)(Ac + offA[mt]);
#pragma unroll
    for (int nt = 0; nt < 4; ++nt) bfr[nt] = *(const bf16x8*)(Bc + offB[nt]);
#pragma unroll
    for (int mt = 0; mt < 4; ++mt)
#pragma unroll
      for (int nt = 0; nt < 4; ++nt)
        acc[mt][nt] = __builtin_amdgcn_mfma_f32_16x16x32_bf16(af[mt], bfr[nt], acc[mt][nt], 0, 0, 0);
  }

#pragma unroll
  for (int mt = 0; mt < 4; ++mt)
#pragma unroll
    for (int nt = 0; nt < 4; ++nt) {
      int n = n0 + wn + nt * 16 + l16;
#pragma unroll
      for (int rg = 0; rg < 4; ++rg) {
        int m = m0 + wm + mt * 16 + quad * 4 + rg;
        float v = acc[mt][nt][rg];
        if (MODE == 0) {
          v = (v * s[(m & 7) * N + n] + bias[n]) * postscale;
          ((u16*)Cout)[(size_t)m * N + n] = f2bf(v);
        } else {
          ((float*)Cout)[(size_t)m * N + n] = v + bias[n];
        }
      }
    }
}

// fused q + kv projection GEMMs, XCD-banded decode.
// 1536 blocks; xcd = blk&7 gets by in [xcd*8, xcd*8+8), bx streams 0..23.
// Per-XCD A working set = 8 panels (4 MB, L2-resident); staging loads hit L2/LLC.
__global__ void k_gemm_qkv(const u16* __restrict__ Xq, const u16* __restrict__ Wq,
                           u16* __restrict__ qout, const float* __restrict__ s_q,
                           const float* __restrict__ b_q, float qscale,
                           const u16* __restrict__ Xkv, const u16* __restrict__ Wkv,
                           u16* __restrict__ kvout, const float* __restrict__ s_kv,
                           const float* __restrict__ b_kv) {
  __shared__ __align__(16) u16 As[2 * 4096];
  __shared__ __align__(16) u16 Bs[2 * 4096];
  const int blk = blockIdx.x;
  const int xcd = blk & 7;
  const int slot = blk >> 3;            // 0..191
  const int bx = slot % 24;
  const int by = xcd * 8 + slot / 24;
  if (bx < 8)
    gemm_tile<0>(Xq, Wq, qout, s_q, b_q, 1024, 1024, qscale, bx, by, As, Bs, threadIdx.x);
  else
    gemm_tile<0>(Xkv, Wkv, kvout, s_kv, b_kv, 2048, 1024, 1.0f, bx - 8, by, As, Bs, threadIdx.x);
}

// output projection GEMM (fp32 out), XCD-banded decode (512 blocks).
__global__ void k_gemm_o(const u16* __restrict__ A, const u16* __restrict__ B,
                         float* __restrict__ Cout, const float* __restrict__ bias) {
  __shared__ __align__(16) u16 As[2 * 4096];
  __shared__ __align__(16) u16 Bs[2 * 4096];
  const int blk = blockIdx.x;
  const int xcd = blk & 7;
  const int slot = blk >> 3;            // 0..63
  const int bx = slot % 8;
  const int by = xcd * 8 + slot / 8;
  gemm_tile<1>(A, B, Cout, nullptr, bias, 1024, 1024, 1.0f, bx, by, As, Bs, threadIdx.x);
}

// ---- V transpose: kv(t,n,c=1,d) -> Vt[n][d][t] ----
__global__ void k_transpose_v(const u16* __restrict__ kv, u16* __restrict__ vt) {
  __shared__ __align__(16) u16 tile[64][72];
  const int tid = threadIdx.x;
  const int n = blockIdx.x >> 4;
  const int t0 = (blockIdx.x & 15) << 6;
#pragma unroll
  for (int it = 0; it < 2; ++it) {
    int r = it * 32 + (tid >> 3);
    int c = (tid & 7) << 3;
    *(uint4*)&tile[r][c] = *(const uint4*)(kv + ((size_t)(t0 + r) * 128 + n) * 128 + 64 + c);
  }
  __syncthreads();
#pragma unroll
  for (int it = 0; it < 2; ++it) {
    int d = it * 32 + (tid >> 3);
    int tc = (tid & 7) << 3;
    u16 v[8];
#pragma unroll
    for (int j = 0; j < 8; ++j) v[j] = tile[tc + j][d];
    uint4 o;
    o.x = (unsigned)v[0] | ((unsigned)v[1] << 16);
    o.y = (unsigned)v[2] | ((unsigned)v[3] << 16);
    o.z = (unsigned)v[4] | ((unsigned)v[5] << 16);
    o.w = (unsigned)v[6] | ((unsigned)v[7] << 16);
    *(uint4*)(vt + ((size_t)n * 64 + d) * 1024 + t0 + tc) = o;
  }
}

// ---- flash attention, G=2: 4 waves x 32 q-cols per 128-q block ----
__global__ __launch_bounds__(256, 3) void k_attn(const u16* __restrict__ qb,
                                                 const u16* __restrict__ kvb,
                                                 const u16* __restrict__ vtb,
                                                 u16* __restrict__ ctx) {
  __shared__ __align__(16) u16 Ks[2][4096];
  __shared__ __align__(16) u16 Vts[2][4096];
  __shared__ __align__(16) u16 Ps[4][32 * 72];  // per wave [q 0..31][key 0..63], stride 72

  const int tid = threadIdx.x;
  const int w = tid >> 6, lane = tid & 63;
  const int quad = lane >> 4, l16 = lane & 15;
  const int n = blockIdx.x & 127;          // head (XCD-swizzled)
  const int q0 = (blockIdx.x >> 7) << 7;   // q-chunk
  const int qw = q0 + w * 32;

  bf16x8 bq[2][2];
#pragma unroll
  for (int g = 0; g < 2; ++g)
#pragma unroll
    for (int ks = 0; ks < 2; ++ks)
      bq[g][ks] = *(const bf16x8*)(qb + ((size_t)(qw + g * 16 + l16) * 128 + n) * 64 + ks * 32 + quad * 8);

  const bool isK = (w < 2);
  const int wv = w & 1;
  const u16* gbase[4];
  u16* lbase[4];
#pragma unroll
  for (int i = 0; i < 4; ++i) {
    int p = (wv * 4 + i) * 64 + lane;
    int r = p >> 3;
    int scb = ((p & 7) ^ (r & 7)) * 8;
    if (isK) {
      gbase[i] = kvb + ((size_t)r * 128 + n) * 128 + scb;   // + tk*16384
      lbase[i] = &Ks[0][(wv * 4 + i) * 512];
    } else {
      gbase[i] = vtb + ((size_t)n * 64 + r) * 1024 + scb;   // + tk
      lbase[i] = &Vts[0][(wv * 4 + i) * 512];
    }
  }
  const size_t gstep = isK ? 16384 : 1;
  const int lstep = 4096;

  float l_i[2] = {0.f, 0.f};
  f32x4 accO[2][4] = {};
  u16* myP = Ps[w];

#pragma unroll
  for (int i = 0; i < 4; ++i) GLD_LDS16(gbase[i], lbase[i]);

#pragma unroll 1
  for (int tk0 = 0; tk0 < 1024; tk0 += 64) {
    const int cur = (tk0 >> 6) & 1;
    __syncthreads();
    if (tk0 < 960) {
      size_t goff = (size_t)(tk0 + 64) * gstep;
#pragma unroll
      for (int i = 0; i < 4; ++i)
        GLD_LDS16(gbase[i] + goff, lbase[i] + (cur ^ 1) * lstep);
    }
    const u16* Kc = Ks[cur];
    const u16* Vc = Vts[cur];

    f32x4 accS[2][4] = {};
#pragma unroll
    for (int mt = 0; mt < 4; ++mt) {
      int r = mt * 16 + l16;
#pragma unroll
      for (int ks = 0; ks < 2; ++ks) {
        bf16x8 ak = *(const bf16x8*)(Kc + r * 64 + (((ks * 4 + quad) ^ (r & 7)) << 3));
#pragma unroll
        for (int g = 0; g < 2; ++g)
          accS[g][mt] = __builtin_amdgcn_mfma_f32_16x16x32_bf16(ak, bq[g][ks], accS[g][mt], 0, 0, 0);
      }
    }

#pragma unroll
    for (int g = 0; g < 2; ++g) {
      float pv[16];
      float ss = 0.f;
#pragma unroll
      for (int mt = 0; mt < 4; ++mt)
#pragma unroll
        for (int rg = 0; rg < 4; ++rg) {
          float p = __builtin_amdgcn_exp2f(accS[g][mt][rg]);
          pv[mt * 4 + rg] = p;
          ss += p;
        }
      ss += __shfl_xor(ss, 16);
      ss += __shfl_xor(ss, 32);
      l_i[g] += ss;
      const int prow = (g * 16 + l16) * 72;
#pragma unroll
      for (int mt = 0; mt < 4; ++mt) {
        unsigned long long pk = (unsigned long long)pk2bf(pv[mt * 4 + 0], pv[mt * 4 + 1])
            | ((unsigned long long)pk2bf(pv[mt * 4 + 2], pv[mt * 4 + 3]) << 32);
        *(unsigned long long*)(myP + prow + mt * 16 + quad * 4) = pk;
      }
    }

    bf16x8 bp[2][2];
#pragma unroll
    for (int g = 0; g < 2; ++g)
#pragma unroll
      for (int ks = 0; ks < 2; ++ks)
        bp[g][ks] = *(const bf16x8*)(myP + (g * 16 + l16) * 72 + ks * 32 + quad * 8);
#pragma unroll
    for (int dt = 0; dt < 4; ++dt) {
      int r = dt * 16 + l16;
#pragma unroll
      for (int ks = 0; ks < 2; ++ks) {
        bf16x8 av = *(const bf16x8*)(Vc + r * 64 + (((ks * 4 + quad) ^ (r & 7)) << 3));
#pragma unroll
        for (int g = 0; g < 2; ++g)
          accO[g][dt] = __builtin_amdgcn_mfma_f32_16x16x32_bf16(av, bp[g][ks], accO[g][dt], 0, 0, 0);
      }
    }
  }

#pragma unroll
  for (int g = 0; g < 2; ++g) {
    float inv = 1.f / l_i[g];
    const size_t obase = ((size_t)(qw + g * 16 + l16) * 128 + n) * 64;
#pragma unroll
    for (int dt = 0; dt < 4; ++dt) {
      unsigned long long pk = (unsigned long long)pk2bf(accO[g][dt][0] * inv, accO[g][dt][1] * inv)
          | ((unsigned long long)pk2bf(accO[g][dt][2] * inv, accO[g][dt][3] * inv) << 32);
      *(unsigned long long*)(ctx + obase + dt * 16 + quad * 4) = pk;
    }
  }
}

extern "C" void kernel_launch(void* const* d_in, const int* in_sizes, int n_in,
                              void* d_out, int out_size, void* d_ws, size_t ws_size,
                              hipStream_t stream) {
  const float* inq  = (const float*)d_in[0];
  const float* inkv = (const float*)d_in[1];
  const float* w_q  = (const float*)d_in[2];
  const float* b_q  = (const float*)d_in[3];
  const float* w_kv = (const float*)d_in[4];
  const float* b_kv = (const float*)d_in[5];
  const float* w_o  = (const float*)d_in[6];
  const float* b_o  = (const float*)d_in[7];
  const float* r_q  = (const float*)d_in[8];
  const float* s_q  = (const float*)d_in[9];
  const float* r_kv = (const float*)d_in[10];
  const float* s_kv = (const float*)d_in[11];

  const size_t MEG = 1024 * 1024;
  u16* ws    = (u16*)d_ws;
  u16* Xq    = ws;               // 8M bf16, later reused as ctx
  u16* Xkv   = ws + 8 * MEG;     // 8M bf16, later reused as Vt
  u16* Wq    = ws + 16 * MEG;    // 1M
  u16* Wkv   = ws + 17 * MEG;    // 2M
  u16* Wo    = ws + 19 * MEG;    // 1M
  u16* qbuf  = ws + 20 * MEG;    // 8M  (t,n,d)
  u16* kvbuf = ws + 28 * MEG;    // 16M (t,n,c,d)
  u16* vt    = Xkv;
  u16* ctx   = Xq;

  k_convert_all<<<20480, 256, 0, stream>>>(inq, r_q, inkv, r_kv, w_q, w_kv, w_o,
                                           Xq, Xkv, Wq, Wkv, Wo);

  const float QSCALE = 0.125f * 1.44269504088896340736f;  // hd^-0.5 * log2e into q
  k_gemm_qkv<<<1536, 256, 0, stream>>>(Xq, Wq, qbuf, s_q, b_q, QSCALE,
                                       Xkv, Wkv, kvbuf, s_kv, b_kv);
  k_transpose_v<<<2048, 256, 0, stream>>>(kvbuf, vt);
  k_attn<<<1024, 256, 0, stream>>>(qbuf, kvbuf, vt, ctx);
  k_gemm_o<<<512, 256, 0, stream>>>(ctx, Wo, (float*)d_out, b_o);
}

// Round 7
// 295.097 us; speedup vs baseline: 1.0667x; 1.0062x over previous
//
#include <hip/hip_runtime.h>
#include <stdint.h>

typedef unsigned short u16;
typedef __bf16 bf16x8 __attribute__((ext_vector_type(8)));
typedef float f32x4 __attribute__((ext_vector_type(4)));

typedef __attribute__((address_space(3))) void lds_void;
typedef const __attribute__((address_space(1))) void gbl_void;
#define GLD_LDS16(g, l) __builtin_amdgcn_global_load_lds((gbl_void*)(g), (lds_void*)(l), 16, 0, 0)

// Relaxed barrier: wait until <=4 of this wave's VMEM remain outstanding
// (the newest 4 = next tile's staging loads), then barrier. Full = drain all.
#define BAR_RELAX() asm volatile("s_waitcnt vmcnt(4)\n\ts_barrier" ::: "memory")
#define BAR_FULL()  asm volatile("s_waitcnt vmcnt(0)\n\ts_barrier" ::: "memory")

__device__ __forceinline__ u16 f2bf(float f) {
  unsigned u = __float_as_uint(f);
  u += 0x7fffu + ((u >> 16) & 1u);   // RNE
  return (u16)(u >> 16);
}

// pack bf16(a) | bf16(b)<<16 with round-half-up via v_perm_b32
__device__ __forceinline__ unsigned pk2bf(float a, float b) {
  unsigned au = __float_as_uint(a) + 0x8000u;
  unsigned bu = __float_as_uint(b) + 0x8000u;
  return __builtin_amdgcn_perm(bu, au, 0x07060302u);
}

// ---- fused prepass: all fp32 -> bf16 conversions in one launch ----
__global__ void k_convert_all(const float* __restrict__ inq, const float* __restrict__ r_q,
                              const float* __restrict__ inkv, const float* __restrict__ r_kv,
                              const float* __restrict__ w_q, const float* __restrict__ w_kv,
                              const float* __restrict__ w_o,
                              u16* __restrict__ Xq, u16* __restrict__ Xkv,
                              u16* __restrict__ Wq, u16* __restrict__ Wkv,
                              u16* __restrict__ Wo) {
  int blk = blockIdx.x;
  const float* src; const float* r = nullptr; u16* dst; int base;
  if (blk < 8192)       { src = inq;  r = r_q;  dst = Xq;  base = 0; }
  else if (blk < 16384) { src = inkv; r = r_kv; dst = Xkv; base = 8192; }
  else if (blk < 17408) { src = w_q;  dst = Wq;  base = 16384; }
  else if (blk < 19456) { src = w_kv; dst = Wkv; base = 17408; }
  else                  { src = w_o;  dst = Wo;  base = 19456; }
  int i4 = ((blk - base) * 256 + threadIdx.x) * 4;
  float4 xv = *(const float4*)(src + i4);
  if (r) {
    int rb = ((i4 >> 10) & 7) * 1024 + (i4 & 1023);
    float4 rv = *(const float4*)(r + rb);
    xv.x *= rv.x; xv.y *= rv.y; xv.z *= rv.z; xv.w *= rv.w;
  }
  unsigned long long pk = (unsigned long long)pk2bf(xv.x, xv.y)
      | ((unsigned long long)pk2bf(xv.z, xv.w) << 32);
  *(unsigned long long*)(dst + i4) = pk;
}

// ---- GEMM tile body: C = A * B^T, 3-stage pipelined LDS, 128x128 tile, BK=32 ----
// MODE 0: bf16 out, C = (acc * s[(m&7)*N+n] + bias[n]) * postscale
// MODE 1: f32 out,  C = acc + bias[n]
// MODE 2: kv mode — K columns (wn==0) -> compact kbuf(t,head,d);
//         V columns (wn==64) -> vt[head][d][t] (fused V-transpose).
//         NOTE: kbuf/vt must NOT alias A (written while other blocks read A).
template <int MODE>
__device__ __forceinline__ void gemm_tile(const u16* __restrict__ A, const u16* __restrict__ B,
                                          void* __restrict__ Cout, const float* __restrict__ s,
                                          const float* __restrict__ bias, int N, int K,
                                          float postscale, int bx, int by,
                                          u16* As, u16* Bs, int tid,
                                          u16* __restrict__ vt, int h) {
  const int w = tid >> 6, lane = tid & 63;
  const int quad = lane >> 4, l16 = lane & 15;
  const int n0 = bx * 128, m0 = by * 128;
  const int wm = (w & 1) * 64, wn = (w >> 1) * 64;

  f32x4 acc[4][4] = {};

  int srow[2], scol[2];
#pragma unroll
  for (int i = 0; i < 2; ++i) {
    int p = (w * 2 + i) * 64 + lane;
    int row = p >> 2;
    int cb = (p & 3) ^ ((row >> 1) & 3);
    srow[i] = row; scol[i] = cb * 8;
  }
  int offA[4], offB[4];
#pragma unroll
  for (int t = 0; t < 4; ++t) {
    int ra = wm + t * 16 + l16;
    offA[t] = ra * 32 + ((quad ^ ((ra >> 1) & 3)) * 8);
    int rb = wn + t * 16 + l16;
    offB[t] = rb * 32 + ((quad ^ ((rb >> 1) & 3)) * 8);
  }

  // prologue: stage k-tiles 0 and 1 into buffers 0 and 1 (4 loads/wave each)
#pragma unroll
  for (int st = 0; st < 2; ++st)
#pragma unroll
    for (int i = 0; i < 2; ++i) {
      GLD_LDS16(A + (size_t)(m0 + srow[i]) * K + st * 32 + scol[i],
                As + st * 4096 + (w * 2 + i) * 512);
      GLD_LDS16(B + (size_t)(n0 + srow[i]) * K + st * 32 + scol[i],
                Bs + st * 4096 + (w * 2 + i) * 512);
    }

  int cur = 0, nxt = 2;
#pragma unroll 1
  for (int k0 = 0; k0 < K; k0 += 32) {
    // tile k's loads (issued 2 iters ago) are the oldest 4; wait them out,
    // leave tile k+1's 4 loads in flight.
    if (k0 + 32 >= K) BAR_FULL(); else BAR_RELAX();

    if (k0 + 64 < K) {
#pragma unroll
      for (int i = 0; i < 2; ++i) {
        GLD_LDS16(A + (size_t)(m0 + srow[i]) * K + (k0 + 64) + scol[i],
                  As + nxt * 4096 + (w * 2 + i) * 512);
        GLD_LDS16(B + (size_t)(n0 + srow[i]) * K + (k0 + 64) + scol[i],
                  Bs + nxt * 4096 + (w * 2 + i) * 512);
      }
    }
    const u16* Ac = As + cur * 4096;
    const u16* Bc = Bs + cur * 4096;
    bf16x8 af[4], bfr[4];
#pragma unroll
    for (int mt = 0; mt < 4; ++mt) af[mt] = *(const bf16x8*)(Ac + offA[mt]);
#pragma unroll
    for (int nt = 0; nt < 4; ++nt) bfr[nt] = *(const bf16x8*)(Bc + offB[nt]);
#pragma unroll
    for (int mt = 0; mt < 4; ++mt)
#pragma unroll
      for (int nt = 0; nt < 4; ++nt)
        acc[mt][nt] = __builtin_amdgcn_mfma_f32_16x16x32_bf16(af[mt], bfr[nt], acc[mt][nt], 0, 0, 0);
    cur = (cur == 2) ? 0 : cur + 1;
    nxt = (nxt == 2) ? 0 : nxt + 1;
  }

#pragma unroll
  for (int mt = 0; mt < 4; ++mt)
#pragma unroll
    for (int nt = 0; nt < 4; ++nt) {
      int n = n0 + wn + nt * 16 + l16;
#pragma unroll
      for (int rg = 0; rg < 4; ++rg) {
        int m = m0 + wm + mt * 16 + quad * 4 + rg;
        float v = acc[mt][nt][rg];
        if (MODE == 0) {
          v = (v * s[(m & 7) * N + n] + bias[n]) * postscale;
          ((u16*)Cout)[(size_t)m * N + n] = f2bf(v);
        } else if (MODE == 1) {
          ((float*)Cout)[(size_t)m * N + n] = v + bias[n];
        } else {  // MODE 2: kv, compact K + fused V transpose
          v = v * s[(m & 7) * N + n] + bias[n];
          int b = m & 7, tk = m >> 3;
          int head = b * 16 + h;
          int dloc = nt * 16 + l16;     // 0..63 within the 64-col half
          if (wn == 0) {
            ((u16*)Cout)[((size_t)(tk * 128 + head)) * 64 + dloc] = f2bf(v);
          } else {
            vt[((size_t)(head * 64 + dloc)) * 1024 + tk] = f2bf(v);
          }
        }
      }
    }
}

// fused q + kv projection GEMMs, XCD-banded decode (1536 blocks).
// kv blocks write compact K and transposed V (fused transpose).
__global__ void k_gemm_qkv(const u16* __restrict__ Xq, const u16* __restrict__ Wq,
                           u16* __restrict__ qout, const float* __restrict__ s_q,
                           const float* __restrict__ b_q, float qscale,
                           const u16* __restrict__ Xkv, const u16* __restrict__ Wkv,
                           u16* __restrict__ kbuf, const float* __restrict__ s_kv,
                           const float* __restrict__ b_kv, u16* __restrict__ vt) {
  __shared__ __align__(16) u16 As[3 * 4096];
  __shared__ __align__(16) u16 Bs[3 * 4096];
  const int blk = blockIdx.x;
  const int xcd = blk & 7;
  const int slot = blk >> 3;            // 0..191
  const int bx = slot % 24;
  const int by = xcd * 8 + slot / 24;
  if (bx < 8)
    gemm_tile<0>(Xq, Wq, qout, s_q, b_q, 1024, 1024, qscale, bx, by, As, Bs,
                 threadIdx.x, nullptr, 0);
  else
    gemm_tile<2>(Xkv, Wkv, kbuf, s_kv, b_kv, 2048, 1024, 1.0f, bx - 8, by, As, Bs,
                 threadIdx.x, vt, bx - 8);
}

// output projection GEMM (fp32 out), XCD-banded decode (512 blocks).
__global__ void k_gemm_o(const u16* __restrict__ A, const u16* __restrict__ B,
                         float* __restrict__ Cout, const float* __restrict__ bias) {
  __shared__ __align__(16) u16 As[3 * 4096];
  __shared__ __align__(16) u16 Bs[3 * 4096];
  const int blk = blockIdx.x;
  const int xcd = blk & 7;
  const int slot = blk >> 3;            // 0..63
  const int bx = slot % 8;
  const int by = xcd * 8 + slot / 8;
  gemm_tile<1>(A, B, Cout, nullptr, bias, 1024, 1024, 1.0f, bx, by, As, Bs,
               threadIdx.x, nullptr, 0);
}

// ---- flash attention, G=2: 4 waves x 32 q-cols per 128-q block ----
// K from compact kbuf(t,head,d); V from vt[head][d][t].
__global__ __launch_bounds__(256, 3) void k_attn(const u16* __restrict__ qb,
                                                 const u16* __restrict__ kb,
                                                 const u16* __restrict__ vtb,
                                                 u16* __restrict__ ctx) {
  __shared__ __align__(16) u16 Ks[2][4096];
  __shared__ __align__(16) u16 Vts[2][4096];
  __shared__ __align__(16) u16 Ps[4][32 * 72];  // per wave [q 0..31][key 0..63], stride 72

  const int tid = threadIdx.x;
  const int w = tid >> 6, lane = tid & 63;
  const int quad = lane >> 4, l16 = lane & 15;
  const int n = blockIdx.x & 127;          // head (XCD-swizzled)
  const int q0 = (blockIdx.x >> 7) << 7;   // q-chunk
  const int qw = q0 + w * 32;

  bf16x8 bq[2][2];
#pragma unroll
  for (int g = 0; g < 2; ++g)
#pragma unroll
    for (int ks = 0; ks < 2; ++ks)
      bq[g][ks] = *(const bf16x8*)(qb + ((size_t)(qw + g * 16 + l16) * 128 + n) * 64 + ks * 32 + quad * 8);

  const bool isK = (w < 2);
  const int wv = w & 1;
  const u16* gbase[4];
  u16* lbase[4];
#pragma unroll
  for (int i = 0; i < 4; ++i) {
    int p = (wv * 4 + i) * 64 + lane;
    int r = p >> 3;
    int scb = ((p & 7) ^ (r & 7)) * 8;
    if (isK) {
      gbase[i] = kb + ((size_t)r * 128 + n) * 64 + scb;     // + tk*8192
      lbase[i] = &Ks[0][(wv * 4 + i) * 512];
    } else {
      gbase[i] = vtb + ((size_t)n * 64 + r) * 1024 + scb;   // + tk
      lbase[i] = &Vts[0][(wv * 4 + i) * 512];
    }
  }
  const size_t gstep = isK ? 8192 : 1;
  const int lstep = 4096;

  float l_i[2] = {0.f, 0.f};
  f32x4 accO[2][4] = {};
  u16* myP = Ps[w];

#pragma unroll
  for (int i = 0; i < 4; ++i) GLD_LDS16(gbase[i], lbase[i]);

#pragma unroll 1
  for (int tk0 = 0; tk0 < 1024; tk0 += 64) {
    const int cur = (tk0 >> 6) & 1;
    __syncthreads();
    if (tk0 < 960) {
      size_t goff = (size_t)(tk0 + 64) * gstep;
#pragma unroll
      for (int i = 0; i < 4; ++i)
        GLD_LDS16(gbase[i] + goff, lbase[i] + (cur ^ 1) * lstep);
    }
    const u16* Kc = Ks[cur];
    const u16* Vc = Vts[cur];

    f32x4 accS[2][4] = {};
#pragma unroll
    for (int mt = 0; mt < 4; ++mt) {
      int r = mt * 16 + l16;
#pragma unroll
      for (int ks = 0; ks < 2; ++ks) {
        bf16x8 ak = *(const bf16x8*)(Kc + r * 64 + (((ks * 4 + quad) ^ (r & 7)) << 3));
#pragma unroll
        for (int g = 0; g < 2; ++g)
          accS[g][mt] = __builtin_amdgcn_mfma_f32_16x16x32_bf16(ak, bq[g][ks], accS[g][mt], 0, 0, 0);
      }
    }

#pragma unroll
    for (int g = 0; g < 2; ++g) {
      float pv[16];
      float ss = 0.f;
#pragma unroll
      for (int mt = 0; mt < 4; ++mt)
#pragma unroll
        for (int rg = 0; rg < 4; ++rg) {
          float p = __builtin_amdgcn_exp2f(accS[g][mt][rg]);
          pv[mt * 4 + rg] = p;
          ss += p;
        }
      ss += __shfl_xor(ss, 16);
      ss += __shfl_xor(ss, 32);
      l_i[g] += ss;
      const int prow = (g * 16 + l16) * 72;
#pragma unroll
      for (int mt = 0; mt < 4; ++mt) {
        unsigned long long pk = (unsigned long long)pk2bf(pv[mt * 4 + 0], pv[mt * 4 + 1])
            | ((unsigned long long)pk2bf(pv[mt * 4 + 2], pv[mt * 4 + 3]) << 32);
        *(unsigned long long*)(myP + prow + mt * 16 + quad * 4) = pk;
      }
    }

    bf16x8 bp[2][2];
#pragma unroll
    for (int g = 0; g < 2; ++g)
#pragma unroll
      for (int ks = 0; ks < 2; ++ks)
        bp[g][ks] = *(const bf16x8*)(myP + (g * 16 + l16) * 72 + ks * 32 + quad * 8);
#pragma unroll
    for (int dt = 0; dt < 4; ++dt) {
      int r = dt * 16 + l16;
#pragma unroll
      for (int ks = 0; ks < 2; ++ks) {
        bf16x8 av = *(const bf16x8*)(Vc + r * 64 + (((ks * 4 + quad) ^ (r & 7)) << 3));
#pragma unroll
        for (int g = 0; g < 2; ++g)
          accO[g][dt] = __builtin_amdgcn_mfma_f32_16x16x32_bf16(av, bp[g][ks], accO[g][dt], 0, 0, 0);
      }
    }
  }

#pragma unroll
  for (int g = 0; g < 2; ++g) {
    float inv = 1.f / l_i[g];
    const size_t obase = ((size_t)(qw + g * 16 + l16) * 128 + n) * 64;
#pragma unroll
    for (int dt = 0; dt < 4; ++dt) {
      unsigned long long pk = (unsigned long long)pk2bf(accO[g][dt][0] * inv, accO[g][dt][1] * inv)
          | ((unsigned long long)pk2bf(accO[g][dt][2] * inv, accO[g][dt][3] * inv) << 32);
      *(unsigned long long*)(ctx + obase + dt * 16 + quad * 4) = pk;
    }
  }
}

extern "C" void kernel_launch(void* const* d_in, const int* in_sizes, int n_in,
                              void* d_out, int out_size, void* d_ws, size_t ws_size,
                              hipStream_t stream) {
  const float* inq  = (const float*)d_in[0];
  const float* inkv = (const float*)d_in[1];
  const float* w_q  = (const float*)d_in[2];
  const float* b_q  = (const float*)d_in[3];
  const float* w_kv = (const float*)d_in[4];
  const float* b_kv = (const float*)d_in[5];
  const float* w_o  = (const float*)d_in[6];
  const float* b_o  = (const float*)d_in[7];
  const float* r_q  = (const float*)d_in[8];
  const float* s_q  = (const float*)d_in[9];
  const float* r_kv = (const float*)d_in[10];
  const float* s_kv = (const float*)d_in[11];

  const size_t MEG = 1024 * 1024;
  u16* ws    = (u16*)d_ws;
  u16* Xq    = ws;               // 8M bf16, later reused as ctx
  u16* Xkv   = ws + 8 * MEG;     // 8M bf16 (NOT reused while gemm_qkv runs)
  u16* Wq    = ws + 16 * MEG;    // 1M
  u16* Wkv   = ws + 17 * MEG;    // 2M
  u16* Wo    = ws + 19 * MEG;    // 1M
  u16* qbuf  = ws + 20 * MEG;    // 8M  (t,head,d)
  u16* kbuf  = ws + 28 * MEG;    // 8M  (t,head,d) compact K
  u16* vt    = ws + 36 * MEG;    // 8M  (head,d,t) transposed V — own region!
  u16* ctx   = Xq;               // total 44M u16 = 88 MB

  k_convert_all<<<20480, 256, 0, stream>>>(inq, r_q, inkv, r_kv, w_q, w_kv, w_o,
                                           Xq, Xkv, Wq, Wkv, Wo);

  const float QSCALE = 0.125f * 1.44269504088896340736f;  // hd^-0.5 * log2e into q
  k_gemm_qkv<<<1536, 256, 0, stream>>>(Xq, Wq, qbuf, s_q, b_q, QSCALE,
                                       Xkv, Wkv, kbuf, s_kv, b_kv, vt);
  k_attn<<<1024, 256, 0, stream>>>(qbuf, kbuf, vt, ctx);
  k_gemm_o<<<512, 256, 0, stream>>>(ctx, Wo, (float*)d_out, b_o);
}